// Round 12
// baseline (79.165 us; speedup 1.0000x reference)
//
#include <hip/hip_runtime.h>
#include <hip/hip_bf16.h>

#define NROWS 4096
#define IN_F 512
#define OUT_F 128
#define NBINS 128
#define NCLS 16
#define EPSV 1e-8f
#define TAUV 0.1f

// C2EXP = -0.5 / sigma^2 * log2(e),  sigma = 0.2
#define C2EXP (-18.0336880f)
#define INV_STEP (12.7f)      // 127 / 10  (bins = linspace(-5,5,128))
#define WRAD 17               // window radius in bins (arg < -36 beyond)

#if defined(__has_builtin)
#if __has_builtin(__builtin_amdgcn_exp2f)
#define EXP2F(x) __builtin_amdgcn_exp2f(x)
#else
#define EXP2F(x) exp2f(x)
#endif
#else
#define EXP2F(x) exp2f(x)
#endif

typedef __attribute__((ext_vector_type(8))) short bf16x8;
typedef __attribute__((ext_vector_type(4))) float f32x4;

__device__ __forceinline__ short cvt_bf16(float x) {
    __hip_bfloat16 h = __float2bfloat16(x);
    return *reinterpret_cast<short*>(&h);
}
__device__ __forceinline__ float bf_to_f(unsigned short u) {
    return __uint_as_float((unsigned int)u << 16);
}

// ---------------- K0: transpose + convert weights to bf16 ----------------
__global__ __launch_bounds__(128) void prep_w(
    const float* __restrict__ W1, const float* __restrict__ W2,
    __hip_bfloat16* __restrict__ W1T, __hip_bfloat16* __restrict__ W2T)
{
    const int n = blockIdx.x;      // 0..127 output row (= original col)
    const int t = threadIdx.x;
    for (int k = t; k < IN_F; k += 128)
        W1T[(size_t)n * IN_F + k] = __float2bfloat16(W1[(size_t)k * OUT_F + n]);
    W2T[(size_t)n * OUT_F + t] = __float2bfloat16(W2[(size_t)t * OUT_F + n]);
}

// ---------------- K1: fused MLP projection (MFMA) + normalize + windowed KDE
//                      + softmax; SM output in bf16. x-only LDS table.
// 512 thr = 8 waves; 16 rows/block; 512 blocks.
__global__ __launch_bounds__(512) void fused_proj_pdf(
    const float* __restrict__ X1, const float* __restrict__ X2,
    const __hip_bfloat16* __restrict__ W1T, const float* __restrict__ b1,
    const __hip_bfloat16* __restrict__ W2T, const float* __restrict__ b2,
    const float* __restrict__ bins, __hip_bfloat16* __restrict__ SM)
{
    __shared__ __hip_bfloat16 xb[16][IN_F + 8];   // 16.6 KB
    __shared__ __hip_bfloat16 h_lds[16][136];     // 4.3 KB
    __shared__ float pout[16][128];               // 8 KB
    __shared__ float rowX[8][2][128];             // 8 KB normalized rows
    __shared__ float bins_s[NBINS];               // 0.5 KB
    const int tid  = threadIdx.x;
    const int wave = tid >> 6;      // 0..7
    const int lane = tid & 63;
    const int lr   = lane & 15;
    const int kg   = lane >> 4;
    const int row0 = blockIdx.x * 16;
    const float* __restrict__ X = (row0 < NROWS) ? X1 : X2;
    const int xr0 = (row0 < NROWS) ? row0 : row0 - NROWS;
    const int col = wave * 16 + lr;

    if (tid < NBINS) bins_s[tid] = bins[tid];

    // ---- Phase 0: stage X tile (16 x 512 f32 -> bf16 LDS), coalesced ----
    for (int i = tid; i < 16 * 128; i += 512) {
        const int r = i >> 7, c4 = i & 127;
        float4 v = *reinterpret_cast<const float4*>(
            X + (size_t)(xr0 + r) * IN_F + c4 * 4);
        short4 s;
        s.x = cvt_bf16(v.x); s.y = cvt_bf16(v.y);
        s.z = cvt_bf16(v.z); s.w = cvt_bf16(v.w);
        *reinterpret_cast<short4*>(&xb[r][c4 * 4]) = s;
    }
    __syncthreads();

    // ---- GEMM1: (16 x 512) * (512 x 16 per wave) ----
    f32x4 acc = {0.f, 0.f, 0.f, 0.f};
    {
        const __hip_bfloat16* __restrict__ wrow = W1T + (size_t)col * IN_F;
        #pragma unroll 4
        for (int ks = 0; ks < IN_F / 32; ++ks) {
            const int kb = ks * 32 + kg * 8;
            bf16x8 a = *reinterpret_cast<const bf16x8*>(&xb[lr][kb]);
            bf16x8 b = *reinterpret_cast<const bf16x8*>(wrow + kb);
            acc = __builtin_amdgcn_mfma_f32_16x16x32_bf16(a, b, acc, 0, 0, 0);
        }
    }
    {
        const float bb = b1[col];
        #pragma unroll
        for (int q = 0; q < 4; ++q)
            h_lds[kg * 4 + q][col] = __float2bfloat16(fmaxf(acc[q] + bb, 0.f));
    }
    __syncthreads();

    // ---- GEMM2: (16 x 128) * (128 x 16 per wave) ----
    f32x4 c2 = {0.f, 0.f, 0.f, 0.f};
    {
        const __hip_bfloat16* __restrict__ w2row = W2T + (size_t)col * OUT_F;
        #pragma unroll
        for (int ks = 0; ks < OUT_F / 32; ++ks) {
            const int kb = ks * 32 + kg * 8;
            bf16x8 a2 = *reinterpret_cast<const bf16x8*>(&h_lds[lr][kb]);
            bf16x8 b2f = *reinterpret_cast<const bf16x8*>(w2row + kb);
            c2 = __builtin_amdgcn_mfma_f32_16x16x32_bf16(a2, b2f, c2, 0, 0, 0);
        }
    }
    {
        const float cb = b2[col];
        #pragma unroll
        for (int q = 0; q < 4; ++q)
            pout[kg * 4 + q][col] = c2[q] + cb;
    }
    __syncthreads();

    // ---- PDF phase: wave handles rows {2*wave, 2*wave+1} ----
    const int m0 = wave * 2, m1 = m0 + 1;

    const float p00 = pout[m0][lane], p01 = pout[m0][lane + 64];
    const float p10 = pout[m1][lane], p11 = pout[m1][lane + 64];

    float s0 = p00 * p00 + p01 * p01;
    float s1 = p10 * p10 + p11 * p11;
    #pragma unroll
    for (int off = 32; off; off >>= 1) {
        s0 += __shfl_xor(s0, off);
        s1 += __shfl_xor(s1, off);
    }
    const float i0 = __frsqrt_rn(s0), i1 = __frsqrt_rn(s1);
    const float x00 = p00 * i0, x01 = p01 * i0;
    const float x10 = p10 * i1, x11 = p11 * i1;

    rowX[wave][0][lane]      = x00;
    rowX[wave][0][lane + 64] = x01;
    rowX[wave][1][lane]      = x10;
    rowX[wave][1][lane + 64] = x11;
    // wave-private LDS, lockstep wave64: compiler orders via lgkmcnt

    // window over both rows: |x|<=1 guarantees imax-imin <= 61 < 64
    float xlo = fminf(fminf(x00, x01), fminf(x10, x11));
    float xhi = fmaxf(fmaxf(x00, x01), fmaxf(x10, x11));
    #pragma unroll
    for (int off = 32; off; off >>= 1) {
        xlo = fminf(xlo, __shfl_xor(xlo, off));
        xhi = fmaxf(xhi, __shfl_xor(xhi, off));
    }
    int imin = (int)floorf((xlo + 5.0f) * INV_STEP) - WRAD;
    int imax = (int)ceilf ((xhi + 5.0f) * INV_STEP) + WRAD;
    imin = imin < 0 ? 0 : (imin > 127 ? 127 : imin);
    imax = imax > 127 ? 127 : (imax < 0 ? 0 : imax);
    if (imax > imin + 63) imax = imin + 63;   // provably never triggers
    const int nact = imax - imin + 1;
    const int j = imin + lane;
    const bool act = (j <= imax);
    const float bj = bins_s[act ? j : imax];

    // KDE hot loop: 1 ds_read_b128 per 4 exps; 4 accumulator chains.
    const float4* __restrict__ x0v = reinterpret_cast<const float4*>(&rowX[wave][0][0]);
    const float4* __restrict__ x1v = reinterpret_cast<const float4*>(&rowX[wave][1][0]);
    float aA0 = 0.f, aA1 = 0.f, aB0 = 0.f, aB1 = 0.f;
    #pragma unroll 4
    for (int q = 0; q < 32; ++q) {
        float4 u = x0v[q];                  // 4 dims of row0
        float4 v = x1v[q];                  // 4 dims of row1
        float t;
        t = u.x - bj; aA0 += EXP2F((C2EXP * t) * t);
        t = u.z - bj; aA1 += EXP2F((C2EXP * t) * t);
        t = v.x - bj; aB0 += EXP2F((C2EXP * t) * t);
        t = v.z - bj; aB1 += EXP2F((C2EXP * t) * t);
        t = u.y - bj; aA0 += EXP2F((C2EXP * t) * t);
        t = u.w - bj; aA1 += EXP2F((C2EXP * t) * t);
        t = v.y - bj; aB0 += EXP2F((C2EXP * t) * t);
        t = v.w - bj; aB1 += EXP2F((C2EXP * t) * t);
    }
    float pdf0 = act ? (aA0 + aA1) * (1.0f / OUT_F) : 0.f;
    float pdf1 = act ? (aB0 + aB1) * (1.0f / OUT_F) : 0.f;

    // normalize over all 128 bins (out-of-window bins are exactly 0)
    float t0 = pdf0, t1 = pdf1;
    #pragma unroll
    for (int off = 32; off; off >>= 1) {
        t0 += __shfl_xor(t0, off);
        t1 += __shfl_xor(t1, off);
    }
    pdf0 *= 1.0f / (t0 + EPSV);
    pdf1 *= 1.0f / (t1 + EPSV);

    // softmax max: values >= 0 and zero-bins are 0, so plain max works
    float mx0 = pdf0, mx1 = pdf1;
    #pragma unroll
    for (int off = 32; off; off >>= 1) {
        mx0 = fmaxf(mx0, __shfl_xor(mx0, off));
        mx1 = fmaxf(mx1, __shfl_xor(mx1, off));
    }
    const float q0 = act ? __expf(pdf0 - mx0) : 0.f;
    const float q1 = act ? __expf(pdf1 - mx1) : 0.f;
    const float ez0 = __expf(-mx0), ez1 = __expf(-mx1);
    float es0 = q0, es1 = q1;
    #pragma unroll
    for (int off = 32; off; off >>= 1) {
        es0 += __shfl_xor(es0, off);
        es1 += __shfl_xor(es1, off);
    }
    es0 += (float)(NBINS - nact) * ez0;
    es1 += (float)(NBINS - nact) * ez1;
    const float r0 = 1.0f / es0, r1 = 1.0f / es1;
    const float z0 = ez0 * r0, z1 = ez1 * r1;

    // scatter windowed values to output bins {lane, lane+64}
    const int sa = lane - imin;
    const int sb = lane + 64 - imin;
    const float w0a = __shfl(q0, sa & 63) * r0;
    const float w0b = __shfl(q0, sb & 63) * r0;
    const float w1a = __shfl(q1, sa & 63) * r1;
    const float w1b = __shfl(q1, sb & 63) * r1;
    const bool ina = (unsigned)sa < (unsigned)nact;
    const bool inb = (unsigned)sb < (unsigned)nact;

    SM[(size_t)(row0 + m0) * OUT_F + lane]      = __float2bfloat16(ina ? w0a : z0);
    SM[(size_t)(row0 + m0) * OUT_F + 64 + lane] = __float2bfloat16(inb ? w0b : z0);
    SM[(size_t)(row0 + m1) * OUT_F + lane]      = __float2bfloat16(ina ? w1a : z1);
    SM[(size_t)(row0 + m1) * OUT_F + 64 + lane] = __float2bfloat16(inb ? w1b : z1);
}

// ---------------- K2: segment partial sums + last-block final tail ----------
// 64 blocks = (batch, seg); partials + ticket; last block computes the loss.
struct RedS {
    unsigned short rows[128][128];   // 32 KB
    int labs[128];
};
struct FinS {
    float PA[32][133], LA[32][133];  // pad 133: gcd(133,32)=1
    float PB[32][133], LB[32][133];
    float J[32][32];
    float pls[32], cnt[32], HA[32], HB[32];
};

__global__ __launch_bounds__(256) void rowred_final(
    const __hip_bfloat16* __restrict__ SM,
    const int* __restrict__ Y1, const int* __restrict__ Y2,
    __hip_bfloat16* __restrict__ pdist, float* __restrict__ pcnt,
    unsigned int* __restrict__ done, float* __restrict__ out)
{
    __shared__ alignas(16) char smem[sizeof(FinS) > sizeof(RedS) ?
                                     sizeof(FinS) : sizeof(RedS)];
    __shared__ bool isLast;
    const int blk = blockIdx.x;           // 0..63
    const int batch = blk >> 5, seg = blk & 31;
    const int tid = threadIdx.x;
    const int* __restrict__ Y = batch ? Y2 : Y1;

    // ---------- phase A: per-segment class partial sums ----------
    {
        RedS& R = *reinterpret_cast<RedS*>(smem);
        const unsigned short* __restrict__ src =
            (const unsigned short*)SM + ((size_t)batch * 4096 + (size_t)seg * 128) * OUT_F;
        unsigned short* dst = &R.rows[0][0];
        for (int i = tid; i < 128 * 128 / 8; i += 256) {
            *reinterpret_cast<uint4*>(dst + i * 8) =
                *reinterpret_cast<const uint4*>(src + i * 8);
        }
        if (tid < 128) R.labs[tid] = Y[seg * 128 + tid];
        __syncthreads();

        const int jq = tid & 31;          // j = jq*4 .. +3
        const int c0 = tid >> 5;          // 0..7; handles c0 and c0+8
        f32x4 acc0 = {0.f, 0.f, 0.f, 0.f};
        f32x4 acc1 = {0.f, 0.f, 0.f, 0.f};
        int cnt0 = 0, cnt1 = 0;
        for (int r = 0; r < 128; ++r) {
            ushort4 v = *reinterpret_cast<const ushort4*>(&R.rows[r][jq * 4]);
            const float f0 = bf_to_f(v.x), f1 = bf_to_f(v.y);
            const float f2 = bf_to_f(v.z), f3 = bf_to_f(v.w);
            const int lab = R.labs[r];
            const float h0 = (lab == c0) ? 1.f : 0.f;
            const float h1 = (lab == c0 + 8) ? 1.f : 0.f;
            acc0.x = fmaf(h0, f0, acc0.x); acc0.y = fmaf(h0, f1, acc0.y);
            acc0.z = fmaf(h0, f2, acc0.z); acc0.w = fmaf(h0, f3, acc0.w);
            acc1.x = fmaf(h1, f0, acc1.x); acc1.y = fmaf(h1, f1, acc1.y);
            acc1.z = fmaf(h1, f2, acc1.z); acc1.w = fmaf(h1, f3, acc1.w);
            cnt0 += (lab == c0);
            cnt1 += (lab == c0 + 8);
        }
        unsigned short* pd = (unsigned short*)pdist;
        const size_t b0 = ((size_t)(batch * 16 + c0) * 128 + jq * 4) * 32 + seg;
        const size_t b1 = ((size_t)(batch * 16 + c0 + 8) * 128 + jq * 4) * 32 + seg;
        pd[b0 +  0] = (unsigned short)cvt_bf16(acc0.x);
        pd[b0 + 32] = (unsigned short)cvt_bf16(acc0.y);
        pd[b0 + 64] = (unsigned short)cvt_bf16(acc0.z);
        pd[b0 + 96] = (unsigned short)cvt_bf16(acc0.w);
        pd[b1 +  0] = (unsigned short)cvt_bf16(acc1.x);
        pd[b1 + 32] = (unsigned short)cvt_bf16(acc1.y);
        pd[b1 + 64] = (unsigned short)cvt_bf16(acc1.z);
        pd[b1 + 96] = (unsigned short)cvt_bf16(acc1.w);
        if (jq == 0) {
            pcnt[(batch * 16 + c0) * 32 + seg]     = (float)cnt0;
            pcnt[(batch * 16 + c0 + 8) * 32 + seg] = (float)cnt1;
        }
    }

    // ---------- ticket: last block runs the tail ----------
    __threadfence();
    __syncthreads();
    if (tid == 0) isLast = (atomicAdd(done, 1u) == 63u);
    __syncthreads();
    if (!isLast) return;
    __threadfence();

    // ---------- phase B: merge partials, means, logs, KL, loss ----------
    {
        FinS& F = *reinterpret_cast<FinS*>(smem);
        const unsigned short* __restrict__ pd = (const unsigned short*)pdist;

        if (tid < 32) {
            float s = 0.f;
            #pragma unroll 8
            for (int sg = 0; sg < 32; ++sg) s += pcnt[tid * 32 + sg];
            F.cnt[tid] = s;
        }

        for (int s = tid; s < 32 * NBINS; s += 256) {
            const int bc = s >> 7, jj = s & 127;
            const uint4* base = reinterpret_cast<const uint4*>(pd + (size_t)s * 32);
            float a = 0.f;
            #pragma unroll
            for (int w = 0; w < 4; ++w) {
                uint4 u = base[w];
                const unsigned short* us = (const unsigned short*)&u;
                #pragma unroll
                for (int e = 0; e < 8; ++e) a += bf_to_f(us[e]);
            }
            if (bc < 16) F.PA[bc][jj] = a;
            else         F.PB[bc - 16][jj] = a;
        }
        __syncthreads();

        for (int s = tid; s < NCLS * NBINS; s += 256) {
            const int c = s >> 7, jj = s & 127;
            const float a = F.PA[c][jj] / F.cnt[c];
            const float b = F.PB[c][jj] / F.cnt[16 + c];
            const float mm = 0.5f * (a + b);
            F.PA[c][jj] = a;        F.LA[c][jj] = __logf(a);
            F.PA[c + 16][jj] = mm;  F.LA[c + 16][jj] = __logf(mm);
            F.PB[c][jj] = b;        F.LB[c][jj] = __logf(b);
            F.PB[c + 16][jj] = mm;  F.LB[c + 16][jj] = __logf(mm);
        }
        __syncthreads();

        if (tid < 64) {
            const int i = tid & 31;
            float h = 0.f;
            if (tid < 32) {
                #pragma unroll 4
                for (int jj = 0; jj < NBINS; ++jj)
                    h = fmaf(F.PA[i][jj], F.LA[i][jj], h);
                F.HA[i] = h;
            } else {
                #pragma unroll 4
                for (int jj = 0; jj < NBINS; ++jj)
                    h = fmaf(F.PB[i][jj], F.LB[i][jj], h);
                F.HB[i] = h;
            }
        }
        __syncthreads();

        for (int p = tid; p < 32 * 32; p += 256) {
            const int i = p >> 5, k = p & 31;
            if (i == k) { F.J[i][k] = 0.f; continue; }
            float cA = 0.f, cB = 0.f;
            #pragma unroll 4
            for (int jj = 0; jj < NBINS; ++jj) {
                cA = fmaf(F.PA[i][jj], F.LA[k][jj], cA);
                cB = fmaf(F.PB[i][jj], F.LB[k][jj], cB);
            }
            F.J[i][k] = 0.5f * ((F.HA[i] - cA) + (F.HB[i] - cB));
        }
        __syncthreads();

        if (tid < 32) {
            float den = 0.f;
            for (int k = 0; k < 32; ++k)
                den += __expf(F.J[tid][k] * (1.0f / TAUV));
            const float pos = F.J[tid][(tid + 16) & 31];
            F.pls[tid] = -(pos * (1.0f / TAUV)) + __logf(den);
        }
        __syncthreads();
        if (tid == 0) {
            float s = 0.f;
            for (int i = 0; i < 32; ++i) s += F.pls[i];
            out[0] = s * (1.0f / 32.0f);
        }
    }
}

extern "C" void kernel_launch(void* const* d_in, const int* in_sizes, int n_in,
                              void* d_out, int out_size, void* d_ws, size_t ws_size,
                              hipStream_t stream)
{
    const float* x1   = (const float*)d_in[0];
    const int*   y1   = (const int*)d_in[1];
    const float* x2   = (const float*)d_in[2];
    const int*   y2   = (const int*)d_in[3];
    const float* W1   = (const float*)d_in[4];
    const float* b1   = (const float*)d_in[5];
    const float* W2   = (const float*)d_in[6];
    const float* b2   = (const float*)d_in[7];
    const float* bins = (const float*)d_in[8];
    float* out = (float*)d_out;

    char* ws = (char*)d_ws;
    __hip_bfloat16* SMb = (__hip_bfloat16*)ws;                    // 2 MB
    char* ws2 = ws + (size_t)8192 * 128 * 2;
    __hip_bfloat16* pdist = (__hip_bfloat16*)ws2;                 // 32*128*32 bf16 = 256 KB
    float* pcnt = (float*)(ws2 + 262144);                         // 32*32 f32 = 4 KB
    unsigned int* done = (unsigned int*)(ws2 + 262144 + 4096);    // 4 B ticket
    __hip_bfloat16* W1T = (__hip_bfloat16*)(ws2 + 262144 + 4096 + 256);
    __hip_bfloat16* W2T = W1T + (size_t)OUT_F * IN_F;

    hipMemsetAsync(done, 0, sizeof(unsigned int), stream);
    prep_w<<<128, 128, 0, stream>>>(W1, W2, W1T, W2T);
    fused_proj_pdf<<<512, 512, 0, stream>>>(x1, x2, W1T, b1, W2T, b2, bins, SMb);
    rowred_final<<<64, 256, 0, stream>>>(SMb, y1, y2, pdist, pcnt, done, out);
}

// Round 13
// 59.483 us; speedup vs baseline: 1.3309x; 1.3309x over previous
//
#include <hip/hip_runtime.h>
#include <hip/hip_bf16.h>

#define NROWS 4096
#define IN_F 512
#define OUT_F 128
#define NBINS 128
#define NCLS 16
#define EPSV 1e-8f
#define TAUV 0.1f

// C2EXP = -0.5 / sigma^2 * log2(e),  sigma = 0.2
#define C2EXP (-18.0336880f)
#define INV_STEP (12.7f)      // 127 / 10  (bins = linspace(-5,5,128))
#define WRAD 17               // window radius in bins (arg < -36 beyond)

#if defined(__has_builtin)
#if __has_builtin(__builtin_amdgcn_exp2f)
#define EXP2F(x) __builtin_amdgcn_exp2f(x)
#else
#define EXP2F(x) exp2f(x)
#endif
#else
#define EXP2F(x) exp2f(x)
#endif

typedef __attribute__((ext_vector_type(8))) short bf16x8;
typedef __attribute__((ext_vector_type(4))) float f32x4;

__device__ __forceinline__ short cvt_bf16(float x) {
    __hip_bfloat16 h = __float2bfloat16(x);
    return *reinterpret_cast<short*>(&h);
}
__device__ __forceinline__ float bf_to_f(unsigned short u) {
    return __uint_as_float((unsigned int)u << 16);
}

// ---------------- K0: transpose + convert weights to bf16 ----------------
__global__ __launch_bounds__(128) void prep_w(
    const float* __restrict__ W1, const float* __restrict__ W2,
    __hip_bfloat16* __restrict__ W1T, __hip_bfloat16* __restrict__ W2T)
{
    const int n = blockIdx.x;      // 0..127 output row (= original col)
    const int t = threadIdx.x;
    for (int k = t; k < IN_F; k += 128)
        W1T[(size_t)n * IN_F + k] = __float2bfloat16(W1[(size_t)k * OUT_F + n]);
    W2T[(size_t)n * OUT_F + t] = __float2bfloat16(W2[(size_t)t * OUT_F + n]);
}

// ---------------- K1: fused MLP projection (MFMA) + normalize + windowed KDE
//                      + softmax; SM output in bf16. x-only LDS table.
// 512 thr = 8 waves; 16 rows/block; 512 blocks.
__global__ __launch_bounds__(512) void fused_proj_pdf(
    const float* __restrict__ X1, const float* __restrict__ X2,
    const __hip_bfloat16* __restrict__ W1T, const float* __restrict__ b1,
    const __hip_bfloat16* __restrict__ W2T, const float* __restrict__ b2,
    const float* __restrict__ bins, __hip_bfloat16* __restrict__ SM)
{
    __shared__ __hip_bfloat16 xb[16][IN_F + 8];   // 16.6 KB
    __shared__ __hip_bfloat16 h_lds[16][136];     // 4.3 KB
    __shared__ float pout[16][128];               // 8 KB
    __shared__ float rowX[8][2][128];             // 8 KB normalized rows
    __shared__ float bins_s[NBINS];               // 0.5 KB
    const int tid  = threadIdx.x;
    const int wave = tid >> 6;      // 0..7
    const int lane = tid & 63;
    const int lr   = lane & 15;
    const int kg   = lane >> 4;
    const int row0 = blockIdx.x * 16;
    const float* __restrict__ X = (row0 < NROWS) ? X1 : X2;
    const int xr0 = (row0 < NROWS) ? row0 : row0 - NROWS;
    const int col = wave * 16 + lr;

    if (tid < NBINS) bins_s[tid] = bins[tid];

    // ---- Phase 0: stage X tile (16 x 512 f32 -> bf16 LDS), coalesced ----
    for (int i = tid; i < 16 * 128; i += 512) {
        const int r = i >> 7, c4 = i & 127;
        float4 v = *reinterpret_cast<const float4*>(
            X + (size_t)(xr0 + r) * IN_F + c4 * 4);
        short4 s;
        s.x = cvt_bf16(v.x); s.y = cvt_bf16(v.y);
        s.z = cvt_bf16(v.z); s.w = cvt_bf16(v.w);
        *reinterpret_cast<short4*>(&xb[r][c4 * 4]) = s;
    }
    __syncthreads();

    // ---- GEMM1: (16 x 512) * (512 x 16 per wave) ----
    f32x4 acc = {0.f, 0.f, 0.f, 0.f};
    {
        const __hip_bfloat16* __restrict__ wrow = W1T + (size_t)col * IN_F;
        #pragma unroll 4
        for (int ks = 0; ks < IN_F / 32; ++ks) {
            const int kb = ks * 32 + kg * 8;
            bf16x8 a = *reinterpret_cast<const bf16x8*>(&xb[lr][kb]);
            bf16x8 b = *reinterpret_cast<const bf16x8*>(wrow + kb);
            acc = __builtin_amdgcn_mfma_f32_16x16x32_bf16(a, b, acc, 0, 0, 0);
        }
    }
    {
        const float bb = b1[col];
        #pragma unroll
        for (int q = 0; q < 4; ++q)
            h_lds[kg * 4 + q][col] = __float2bfloat16(fmaxf(acc[q] + bb, 0.f));
    }
    __syncthreads();

    // ---- GEMM2: (16 x 128) * (128 x 16 per wave) ----
    f32x4 c2 = {0.f, 0.f, 0.f, 0.f};
    {
        const __hip_bfloat16* __restrict__ w2row = W2T + (size_t)col * OUT_F;
        #pragma unroll
        for (int ks = 0; ks < OUT_F / 32; ++ks) {
            const int kb = ks * 32 + kg * 8;
            bf16x8 a2 = *reinterpret_cast<const bf16x8*>(&h_lds[lr][kb]);
            bf16x8 b2f = *reinterpret_cast<const bf16x8*>(w2row + kb);
            c2 = __builtin_amdgcn_mfma_f32_16x16x32_bf16(a2, b2f, c2, 0, 0, 0);
        }
    }
    {
        const float cb = b2[col];
        #pragma unroll
        for (int q = 0; q < 4; ++q)
            pout[kg * 4 + q][col] = c2[q] + cb;
    }
    __syncthreads();

    // ---- PDF phase: wave handles rows {2*wave, 2*wave+1} ----
    const int m0 = wave * 2, m1 = m0 + 1;

    const float p00 = pout[m0][lane], p01 = pout[m0][lane + 64];
    const float p10 = pout[m1][lane], p11 = pout[m1][lane + 64];

    float s0 = p00 * p00 + p01 * p01;
    float s1 = p10 * p10 + p11 * p11;
    #pragma unroll
    for (int off = 32; off; off >>= 1) {
        s0 += __shfl_xor(s0, off);
        s1 += __shfl_xor(s1, off);
    }
    const float i0 = __frsqrt_rn(s0), i1 = __frsqrt_rn(s1);
    const float x00 = p00 * i0, x01 = p01 * i0;
    const float x10 = p10 * i1, x11 = p11 * i1;

    rowX[wave][0][lane]      = x00;
    rowX[wave][0][lane + 64] = x01;
    rowX[wave][1][lane]      = x10;
    rowX[wave][1][lane + 64] = x11;
    // wave-private LDS, lockstep wave64: compiler orders via lgkmcnt

    // window over both rows: |x|<=1 guarantees imax-imin <= 61 < 64
    float xlo = fminf(fminf(x00, x01), fminf(x10, x11));
    float xhi = fmaxf(fmaxf(x00, x01), fmaxf(x10, x11));
    #pragma unroll
    for (int off = 32; off; off >>= 1) {
        xlo = fminf(xlo, __shfl_xor(xlo, off));
        xhi = fmaxf(xhi, __shfl_xor(xhi, off));
    }
    int imin = (int)floorf((xlo + 5.0f) * INV_STEP) - WRAD;
    int imax = (int)ceilf ((xhi + 5.0f) * INV_STEP) + WRAD;
    imin = imin < 0 ? 0 : (imin > 127 ? 127 : imin);
    imax = imax > 127 ? 127 : (imax < 0 ? 0 : imax);
    if (imax > imin + 63) imax = imin + 63;   // provably never triggers
    const int nact = imax - imin + 1;
    const int j = imin + lane;
    const bool act = (j <= imax);
    const float bj = bins_s[act ? j : imax];

    // KDE hot loop: 2 ds_read_b128 per 8 exps; 4 accumulator chains.
    const float4* __restrict__ x0v = reinterpret_cast<const float4*>(&rowX[wave][0][0]);
    const float4* __restrict__ x1v = reinterpret_cast<const float4*>(&rowX[wave][1][0]);
    float aA0 = 0.f, aA1 = 0.f, aB0 = 0.f, aB1 = 0.f;
    #pragma unroll 4
    for (int q = 0; q < 32; ++q) {
        float4 u = x0v[q];                  // 4 dims of row0
        float4 v = x1v[q];                  // 4 dims of row1
        float t;
        t = u.x - bj; aA0 += EXP2F((C2EXP * t) * t);
        t = u.z - bj; aA1 += EXP2F((C2EXP * t) * t);
        t = v.x - bj; aB0 += EXP2F((C2EXP * t) * t);
        t = v.z - bj; aB1 += EXP2F((C2EXP * t) * t);
        t = u.y - bj; aA0 += EXP2F((C2EXP * t) * t);
        t = u.w - bj; aA1 += EXP2F((C2EXP * t) * t);
        t = v.y - bj; aB0 += EXP2F((C2EXP * t) * t);
        t = v.w - bj; aB1 += EXP2F((C2EXP * t) * t);
    }
    float pdf0 = act ? (aA0 + aA1) * (1.0f / OUT_F) : 0.f;
    float pdf1 = act ? (aB0 + aB1) * (1.0f / OUT_F) : 0.f;

    // normalize over all 128 bins (out-of-window bins are exactly 0)
    float t0 = pdf0, t1 = pdf1;
    #pragma unroll
    for (int off = 32; off; off >>= 1) {
        t0 += __shfl_xor(t0, off);
        t1 += __shfl_xor(t1, off);
    }
    pdf0 *= 1.0f / (t0 + EPSV);
    pdf1 *= 1.0f / (t1 + EPSV);

    // softmax max: values >= 0 and zero-bins are 0, so plain max works
    float mx0 = pdf0, mx1 = pdf1;
    #pragma unroll
    for (int off = 32; off; off >>= 1) {
        mx0 = fmaxf(mx0, __shfl_xor(mx0, off));
        mx1 = fmaxf(mx1, __shfl_xor(mx1, off));
    }
    const float q0 = act ? __expf(pdf0 - mx0) : 0.f;
    const float q1 = act ? __expf(pdf1 - mx1) : 0.f;
    const float ez0 = __expf(-mx0), ez1 = __expf(-mx1);
    float es0 = q0, es1 = q1;
    #pragma unroll
    for (int off = 32; off; off >>= 1) {
        es0 += __shfl_xor(es0, off);
        es1 += __shfl_xor(es1, off);
    }
    es0 += (float)(NBINS - nact) * ez0;
    es1 += (float)(NBINS - nact) * ez1;
    const float r0 = 1.0f / es0, r1 = 1.0f / es1;
    const float z0 = ez0 * r0, z1 = ez1 * r1;

    // scatter windowed values to output bins {lane, lane+64}
    const int sa = lane - imin;
    const int sb = lane + 64 - imin;
    const float w0a = __shfl(q0, sa & 63) * r0;
    const float w0b = __shfl(q0, sb & 63) * r0;
    const float w1a = __shfl(q1, sa & 63) * r1;
    const float w1b = __shfl(q1, sb & 63) * r1;
    const bool ina = (unsigned)sa < (unsigned)nact;
    const bool inb = (unsigned)sb < (unsigned)nact;

    SM[(size_t)(row0 + m0) * OUT_F + lane]      = __float2bfloat16(ina ? w0a : z0);
    SM[(size_t)(row0 + m0) * OUT_F + 64 + lane] = __float2bfloat16(inb ? w0b : z0);
    SM[(size_t)(row0 + m1) * OUT_F + lane]      = __float2bfloat16(ina ? w1a : z1);
    SM[(size_t)(row0 + m1) * OUT_F + 64 + lane] = __float2bfloat16(inb ? w1b : z1);
}

// ---------------- K2: per-block class partial sums (deterministic) ----------
// 64 blocks = (batch, seg); each owns 128 contiguous rows; reads SM once.
// pdist layout: [(batch*16 + c)*128 + j]*32 + seg   (bf16)
__global__ __launch_bounds__(256) void rowred_kernel(
    const __hip_bfloat16* __restrict__ SM,
    const int* __restrict__ Y1, const int* __restrict__ Y2,
    __hip_bfloat16* __restrict__ pdist, float* __restrict__ pcnt)
{
    __shared__ unsigned short rows_s[128][128];   // 32 KB bf16
    __shared__ int labs[128];
    const int blk = blockIdx.x;           // 0..63
    const int batch = blk >> 5, seg = blk & 31;
    const int tid = threadIdx.x;
    const int* __restrict__ Y = batch ? Y2 : Y1;

    {
        const unsigned short* __restrict__ src =
            (const unsigned short*)SM + ((size_t)batch * 4096 + (size_t)seg * 128) * OUT_F;
        unsigned short* dst = &rows_s[0][0];
        for (int i = tid; i < 128 * 128 / 8; i += 256) {
            *reinterpret_cast<uint4*>(dst + i * 8) =
                *reinterpret_cast<const uint4*>(src + i * 8);
        }
    }
    if (tid < 128) labs[tid] = Y[seg * 128 + tid];
    __syncthreads();

    const int jq = tid & 31;              // j = jq*4 .. +3
    const int c0 = tid >> 5;              // 0..7; handles c0 and c0+8
    f32x4 acc0 = {0.f, 0.f, 0.f, 0.f};
    f32x4 acc1 = {0.f, 0.f, 0.f, 0.f};
    int cnt0 = 0, cnt1 = 0;
    for (int r = 0; r < 128; ++r) {
        ushort4 v = *reinterpret_cast<const ushort4*>(&rows_s[r][jq * 4]);
        const float f0 = bf_to_f(v.x), f1 = bf_to_f(v.y);
        const float f2 = bf_to_f(v.z), f3 = bf_to_f(v.w);
        const int lab = labs[r];
        const float h0 = (lab == c0) ? 1.f : 0.f;
        const float h1 = (lab == c0 + 8) ? 1.f : 0.f;
        acc0.x = fmaf(h0, f0, acc0.x); acc0.y = fmaf(h0, f1, acc0.y);
        acc0.z = fmaf(h0, f2, acc0.z); acc0.w = fmaf(h0, f3, acc0.w);
        acc1.x = fmaf(h1, f0, acc1.x); acc1.y = fmaf(h1, f1, acc1.y);
        acc1.z = fmaf(h1, f2, acc1.z); acc1.w = fmaf(h1, f3, acc1.w);
        cnt0 += (lab == c0);
        cnt1 += (lab == c0 + 8);
    }
    {
        unsigned short* pd = (unsigned short*)pdist;
        const size_t b0 = ((size_t)(batch * 16 + c0) * 128 + jq * 4) * 32 + seg;
        const size_t b1 = ((size_t)(batch * 16 + c0 + 8) * 128 + jq * 4) * 32 + seg;
        pd[b0 +  0] = (unsigned short)cvt_bf16(acc0.x);
        pd[b0 + 32] = (unsigned short)cvt_bf16(acc0.y);
        pd[b0 + 64] = (unsigned short)cvt_bf16(acc0.z);
        pd[b0 + 96] = (unsigned short)cvt_bf16(acc0.w);
        pd[b1 +  0] = (unsigned short)cvt_bf16(acc1.x);
        pd[b1 + 32] = (unsigned short)cvt_bf16(acc1.y);
        pd[b1 + 64] = (unsigned short)cvt_bf16(acc1.z);
        pd[b1 + 96] = (unsigned short)cvt_bf16(acc1.w);
    }
    if (jq == 0) {
        pcnt[(batch * 16 + c0) * 32 + seg]     = (float)cnt0;
        pcnt[(batch * 16 + c0 + 8) * 32 + seg] = (float)cnt1;
    }
}

// ---------------- K3: merge partials, class means, KL matrix, loss ----------
__global__ __launch_bounds__(512) void final_kernel(
    const __hip_bfloat16* __restrict__ pdist, const float* __restrict__ pcnt,
    float* __restrict__ out)
{
    __shared__ float PA[32][133], LA[32][133];   // pad 133: gcd(133,32)=1
    __shared__ float PB[32][133], LB[32][133];
    __shared__ float J[32][32];
    __shared__ float pls[32];
    __shared__ float cnt[32];
    __shared__ float HA[32], HB[32];
    const int tid = threadIdx.x;
    const unsigned short* __restrict__ pd = (const unsigned short*)pdist;

    if (tid < 32) {
        float s = 0.f;
        #pragma unroll 8
        for (int seg = 0; seg < 32; ++seg) s += pcnt[tid * 32 + seg];
        cnt[tid] = s;
    }

    // merge 32 seg-partials per (bc, j) slot: contiguous 32 bf16 = 4 uint4
    for (int s = tid; s < 32 * NBINS; s += 512) {
        const int bc = s >> 7, jj = s & 127;
        const uint4* base = reinterpret_cast<const uint4*>(pd + (size_t)s * 32);
        float a = 0.f;
        #pragma unroll
        for (int w = 0; w < 4; ++w) {
            uint4 u = base[w];
            const unsigned short* us = (const unsigned short*)&u;
            #pragma unroll
            for (int e = 0; e < 8; ++e) a += bf_to_f(us[e]);
        }
        if (bc < 16) PA[bc][jj] = a;
        else         PB[bc - 16][jj] = a;
    }
    __syncthreads();

    // class means, mixture, logs
    for (int s = tid; s < NCLS * NBINS; s += 512) {
        const int c = s >> 7, jj = s & 127;
        const float a = PA[c][jj] / cnt[c];
        const float b = PB[c][jj] / cnt[16 + c];
        const float mm = 0.5f * (a + b);
        PA[c][jj] = a;        LA[c][jj] = __logf(a);
        PA[c + 16][jj] = mm;  LA[c + 16][jj] = __logf(mm);
        PB[c][jj] = b;        LB[c][jj] = __logf(b);
        PB[c + 16][jj] = mm;  LB[c + 16][jj] = __logf(mm);
    }
    __syncthreads();

    // self terms H[i] = sum_j P[i][j] * L[i][j]
    if (tid < 64) {
        const int i = tid & 31;
        float h = 0.f;
        if (tid < 32) {
            #pragma unroll 4
            for (int jj = 0; jj < NBINS; ++jj) h = fmaf(PA[i][jj], LA[i][jj], h);
            HA[i] = h;
        } else {
            #pragma unroll 4
            for (int jj = 0; jj < NBINS; ++jj) h = fmaf(PB[i][jj], LB[i][jj], h);
            HB[i] = h;
        }
    }
    __syncthreads();

    // KL: J[i][k] = 0.5*((HA[i] - sum PA[i]LA[k]) + (HB[i] - sum PB[i]LB[k]))
    for (int p = tid; p < 32 * 32; p += 512) {
        const int i = p >> 5, k = p & 31;
        if (i == k) { J[i][k] = 0.f; continue; }
        float cA = 0.f, cB = 0.f;
        #pragma unroll 4
        for (int jj = 0; jj < NBINS; ++jj) {
            cA = fmaf(PA[i][jj], LA[k][jj], cA);
            cB = fmaf(PB[i][jj], LB[k][jj], cB);
        }
        J[i][k] = 0.5f * ((HA[i] - cA) + (HB[i] - cB));
    }
    __syncthreads();

    if (tid < 32) {
        float den = 0.f;
        for (int k = 0; k < 32; ++k) den += __expf(J[tid][k] * (1.0f / TAUV));
        const float pos = J[tid][(tid + 16) & 31];
        pls[tid] = -(pos * (1.0f / TAUV)) + __logf(den);
    }
    __syncthreads();
    if (tid == 0) {
        float s = 0.f;
        for (int i = 0; i < 32; ++i) s += pls[i];
        out[0] = s * (1.0f / 32.0f);
    }
}

extern "C" void kernel_launch(void* const* d_in, const int* in_sizes, int n_in,
                              void* d_out, int out_size, void* d_ws, size_t ws_size,
                              hipStream_t stream)
{
    const float* x1   = (const float*)d_in[0];
    const int*   y1   = (const int*)d_in[1];
    const float* x2   = (const float*)d_in[2];
    const int*   y2   = (const int*)d_in[3];
    const float* W1   = (const float*)d_in[4];
    const float* b1   = (const float*)d_in[5];
    const float* W2   = (const float*)d_in[6];
    const float* b2   = (const float*)d_in[7];
    const float* bins = (const float*)d_in[8];
    float* out = (float*)d_out;

    char* ws = (char*)d_ws;
    __hip_bfloat16* SMb = (__hip_bfloat16*)ws;                    // 2 MB
    char* ws2 = ws + (size_t)8192 * 128 * 2;
    __hip_bfloat16* pdist = (__hip_bfloat16*)ws2;                 // 32*128*32 bf16 = 256 KB
    float* pcnt = (float*)(ws2 + (size_t)32 * NBINS * 32 * 2);    // 32*32 f32
    __hip_bfloat16* W1T = (__hip_bfloat16*)(ws2 + (size_t)32 * NBINS * 32 * 2 + 8192);
    __hip_bfloat16* W2T = W1T + (size_t)OUT_F * IN_F;

    prep_w<<<128, 128, 0, stream>>>(W1, W2, W1T, W2T);
    fused_proj_pdf<<<512, 512, 0, stream>>>(x1, x2, W1T, b1, W2T, b2, bins, SMb);
    rowred_kernel<<<64, 256, 0, stream>>>(SMb, y1, y2, pdist, pcnt);
    final_kernel<<<1, 512, 0, stream>>>(pdist, pcnt, out);
}

// Round 14
// 53.588 us; speedup vs baseline: 1.4773x; 1.1100x over previous
//
#include <hip/hip_runtime.h>
#include <hip/hip_bf16.h>

#define NROWS 4096
#define IN_F 512
#define OUT_F 128
#define NBINS 128
#define NCLS 16
#define EPSV 1e-8f
#define TAUV 0.1f

// C2EXP = -0.5 / sigma^2 * log2(e),  sigma = 0.2
#define C2EXP (-18.0336880f)
#define INV_STEP (12.7f)      // 127 / 10  (bins = linspace(-5,5,128))
#define WRAD 17               // window radius in bins (arg < -36 beyond)

#if defined(__has_builtin)
#if __has_builtin(__builtin_amdgcn_exp2f)
#define EXP2F(x) __builtin_amdgcn_exp2f(x)
#else
#define EXP2F(x) exp2f(x)
#endif
#else
#define EXP2F(x) exp2f(x)
#endif

typedef __attribute__((ext_vector_type(8))) short bf16x8;
typedef __attribute__((ext_vector_type(4))) float f32x4;

__device__ __forceinline__ short cvt_bf16(float x) {
    __hip_bfloat16 h = __float2bfloat16(x);
    return *reinterpret_cast<short*>(&h);
}
__device__ __forceinline__ float bf_to_f(unsigned short u) {
    return __uint_as_float((unsigned int)u << 16);
}

// ---------------- K0: transpose + convert weights to bf16 ----------------
__global__ __launch_bounds__(128) void prep_w(
    const float* __restrict__ W1, const float* __restrict__ W2,
    __hip_bfloat16* __restrict__ W1T, __hip_bfloat16* __restrict__ W2T)
{
    const int n = blockIdx.x;      // 0..127 output row (= original col)
    const int t = threadIdx.x;
    for (int k = t; k < IN_F; k += 128)
        W1T[(size_t)n * IN_F + k] = __float2bfloat16(W1[(size_t)k * OUT_F + n]);
    W2T[(size_t)n * OUT_F + t] = __float2bfloat16(W2[(size_t)t * OUT_F + n]);
}

// ---------------- K1: fused MLP projection (MFMA) + normalize + windowed KDE
//                      + softmax; SM output in bf16. x-only LDS table.
// 512 thr = 8 waves; 16 rows/block; 512 blocks.
__global__ __launch_bounds__(512) void fused_proj_pdf(
    const float* __restrict__ X1, const float* __restrict__ X2,
    const __hip_bfloat16* __restrict__ W1T, const float* __restrict__ b1,
    const __hip_bfloat16* __restrict__ W2T, const float* __restrict__ b2,
    const float* __restrict__ bins, __hip_bfloat16* __restrict__ SM)
{
    __shared__ __hip_bfloat16 xb[16][IN_F + 8];   // 16.6 KB
    __shared__ __hip_bfloat16 h_lds[16][136];     // 4.3 KB
    __shared__ float pout[16][128];               // 8 KB
    __shared__ float rowX[8][2][128];             // 8 KB normalized rows
    __shared__ float bins_s[NBINS];               // 0.5 KB
    const int tid  = threadIdx.x;
    const int wave = tid >> 6;      // 0..7
    const int lane = tid & 63;
    const int lr   = lane & 15;
    const int kg   = lane >> 4;
    const int row0 = blockIdx.x * 16;
    const float* __restrict__ X = (row0 < NROWS) ? X1 : X2;
    const int xr0 = (row0 < NROWS) ? row0 : row0 - NROWS;
    const int col = wave * 16 + lr;

    if (tid < NBINS) bins_s[tid] = bins[tid];

    // ---- Phase 0: stage X tile (16 x 512 f32 -> bf16 LDS), coalesced ----
    for (int i = tid; i < 16 * 128; i += 512) {
        const int r = i >> 7, c4 = i & 127;
        float4 v = *reinterpret_cast<const float4*>(
            X + (size_t)(xr0 + r) * IN_F + c4 * 4);
        short4 s;
        s.x = cvt_bf16(v.x); s.y = cvt_bf16(v.y);
        s.z = cvt_bf16(v.z); s.w = cvt_bf16(v.w);
        *reinterpret_cast<short4*>(&xb[r][c4 * 4]) = s;
    }
    __syncthreads();

    // ---- GEMM1: (16 x 512) * (512 x 16 per wave) ----
    f32x4 acc = {0.f, 0.f, 0.f, 0.f};
    {
        const __hip_bfloat16* __restrict__ wrow = W1T + (size_t)col * IN_F;
        #pragma unroll 4
        for (int ks = 0; ks < IN_F / 32; ++ks) {
            const int kb = ks * 32 + kg * 8;
            bf16x8 a = *reinterpret_cast<const bf16x8*>(&xb[lr][kb]);
            bf16x8 b = *reinterpret_cast<const bf16x8*>(wrow + kb);
            acc = __builtin_amdgcn_mfma_f32_16x16x32_bf16(a, b, acc, 0, 0, 0);
        }
    }
    {
        const float bb = b1[col];
        #pragma unroll
        for (int q = 0; q < 4; ++q)
            h_lds[kg * 4 + q][col] = __float2bfloat16(fmaxf(acc[q] + bb, 0.f));
    }
    __syncthreads();

    // ---- GEMM2: (16 x 128) * (128 x 16 per wave) ----
    f32x4 c2 = {0.f, 0.f, 0.f, 0.f};
    {
        const __hip_bfloat16* __restrict__ w2row = W2T + (size_t)col * OUT_F;
        #pragma unroll
        for (int ks = 0; ks < OUT_F / 32; ++ks) {
            const int kb = ks * 32 + kg * 8;
            bf16x8 a2 = *reinterpret_cast<const bf16x8*>(&h_lds[lr][kb]);
            bf16x8 b2f = *reinterpret_cast<const bf16x8*>(w2row + kb);
            c2 = __builtin_amdgcn_mfma_f32_16x16x32_bf16(a2, b2f, c2, 0, 0, 0);
        }
    }
    {
        const float cb = b2[col];
        #pragma unroll
        for (int q = 0; q < 4; ++q)
            pout[kg * 4 + q][col] = c2[q] + cb;
    }
    __syncthreads();

    // ---- PDF phase: wave handles rows {2*wave, 2*wave+1} ----
    const int m0 = wave * 2, m1 = m0 + 1;

    const float p00 = pout[m0][lane], p01 = pout[m0][lane + 64];
    const float p10 = pout[m1][lane], p11 = pout[m1][lane + 64];

    float s0 = p00 * p00 + p01 * p01;
    float s1 = p10 * p10 + p11 * p11;
    #pragma unroll
    for (int off = 32; off; off >>= 1) {
        s0 += __shfl_xor(s0, off);
        s1 += __shfl_xor(s1, off);
    }
    const float i0 = __frsqrt_rn(s0), i1 = __frsqrt_rn(s1);
    const float x00 = p00 * i0, x01 = p01 * i0;
    const float x10 = p10 * i1, x11 = p11 * i1;

    rowX[wave][0][lane]      = x00;
    rowX[wave][0][lane + 64] = x01;
    rowX[wave][1][lane]      = x10;
    rowX[wave][1][lane + 64] = x11;
    // wave-private LDS, lockstep wave64: compiler orders via lgkmcnt

    // window over both rows: |x|<=1 guarantees imax-imin <= 61 < 64
    float xlo = fminf(fminf(x00, x01), fminf(x10, x11));
    float xhi = fmaxf(fmaxf(x00, x01), fmaxf(x10, x11));
    #pragma unroll
    for (int off = 32; off; off >>= 1) {
        xlo = fminf(xlo, __shfl_xor(xlo, off));
        xhi = fmaxf(xhi, __shfl_xor(xhi, off));
    }
    int imin = (int)floorf((xlo + 5.0f) * INV_STEP) - WRAD;
    int imax = (int)ceilf ((xhi + 5.0f) * INV_STEP) + WRAD;
    imin = imin < 0 ? 0 : (imin > 127 ? 127 : imin);
    imax = imax > 127 ? 127 : (imax < 0 ? 0 : imax);
    if (imax > imin + 63) imax = imin + 63;   // provably never triggers
    const int nact = imax - imin + 1;
    const int j = imin + lane;
    const bool act = (j <= imax);
    const float bj = bins_s[act ? j : imax];

    // KDE hot loop: 2 ds_read_b128 per 8 exps; 4 accumulator chains.
    const float4* __restrict__ x0v = reinterpret_cast<const float4*>(&rowX[wave][0][0]);
    const float4* __restrict__ x1v = reinterpret_cast<const float4*>(&rowX[wave][1][0]);
    float aA0 = 0.f, aA1 = 0.f, aB0 = 0.f, aB1 = 0.f;
    #pragma unroll 4
    for (int q = 0; q < 32; ++q) {
        float4 u = x0v[q];                  // 4 dims of row0
        float4 v = x1v[q];                  // 4 dims of row1
        float t;
        t = u.x - bj; aA0 += EXP2F((C2EXP * t) * t);
        t = u.z - bj; aA1 += EXP2F((C2EXP * t) * t);
        t = v.x - bj; aB0 += EXP2F((C2EXP * t) * t);
        t = v.z - bj; aB1 += EXP2F((C2EXP * t) * t);
        t = u.y - bj; aA0 += EXP2F((C2EXP * t) * t);
        t = u.w - bj; aA1 += EXP2F((C2EXP * t) * t);
        t = v.y - bj; aB0 += EXP2F((C2EXP * t) * t);
        t = v.w - bj; aB1 += EXP2F((C2EXP * t) * t);
    }
    float pdf0 = act ? (aA0 + aA1) * (1.0f / OUT_F) : 0.f;
    float pdf1 = act ? (aB0 + aB1) * (1.0f / OUT_F) : 0.f;

    // normalize over all 128 bins (out-of-window bins are exactly 0)
    float t0 = pdf0, t1 = pdf1;
    #pragma unroll
    for (int off = 32; off; off >>= 1) {
        t0 += __shfl_xor(t0, off);
        t1 += __shfl_xor(t1, off);
    }
    pdf0 *= 1.0f / (t0 + EPSV);
    pdf1 *= 1.0f / (t1 + EPSV);

    // softmax max: values >= 0 and zero-bins are 0, so plain max works
    float mx0 = pdf0, mx1 = pdf1;
    #pragma unroll
    for (int off = 32; off; off >>= 1) {
        mx0 = fmaxf(mx0, __shfl_xor(mx0, off));
        mx1 = fmaxf(mx1, __shfl_xor(mx1, off));
    }
    const float q0 = act ? __expf(pdf0 - mx0) : 0.f;
    const float q1 = act ? __expf(pdf1 - mx1) : 0.f;
    const float ez0 = __expf(-mx0), ez1 = __expf(-mx1);
    float es0 = q0, es1 = q1;
    #pragma unroll
    for (int off = 32; off; off >>= 1) {
        es0 += __shfl_xor(es0, off);
        es1 += __shfl_xor(es1, off);
    }
    es0 += (float)(NBINS - nact) * ez0;
    es1 += (float)(NBINS - nact) * ez1;
    const float r0 = 1.0f / es0, r1 = 1.0f / es1;
    const float z0 = ez0 * r0, z1 = ez1 * r1;

    // scatter windowed values to output bins {lane, lane+64}
    const int sa = lane - imin;
    const int sb = lane + 64 - imin;
    const float w0a = __shfl(q0, sa & 63) * r0;
    const float w0b = __shfl(q0, sb & 63) * r0;
    const float w1a = __shfl(q1, sa & 63) * r1;
    const float w1b = __shfl(q1, sb & 63) * r1;
    const bool ina = (unsigned)sa < (unsigned)nact;
    const bool inb = (unsigned)sb < (unsigned)nact;

    SM[(size_t)(row0 + m0) * OUT_F + lane]      = __float2bfloat16(ina ? w0a : z0);
    SM[(size_t)(row0 + m0) * OUT_F + 64 + lane] = __float2bfloat16(inb ? w0b : z0);
    SM[(size_t)(row0 + m1) * OUT_F + lane]      = __float2bfloat16(ina ? w1a : z1);
    SM[(size_t)(row0 + m1) * OUT_F + 64 + lane] = __float2bfloat16(inb ? w1b : z1);
}

// ---------------- K2: per-block class partial sums (deterministic) ----------
// 64 blocks = (batch, seg); each owns 128 contiguous rows; reads SM once.
// pdist layout: [(batch*16 + c)*128 + j]*32 + seg   (bf16)
__global__ __launch_bounds__(256) void rowred_kernel(
    const __hip_bfloat16* __restrict__ SM,
    const int* __restrict__ Y1, const int* __restrict__ Y2,
    __hip_bfloat16* __restrict__ pdist, float* __restrict__ pcnt)
{
    __shared__ unsigned short rows_s[128][128];   // 32 KB bf16
    __shared__ int labs[128];
    const int blk = blockIdx.x;           // 0..63
    const int batch = blk >> 5, seg = blk & 31;
    const int tid = threadIdx.x;
    const int* __restrict__ Y = batch ? Y2 : Y1;

    {
        const unsigned short* __restrict__ src =
            (const unsigned short*)SM + ((size_t)batch * 4096 + (size_t)seg * 128) * OUT_F;
        unsigned short* dst = &rows_s[0][0];
        for (int i = tid; i < 128 * 128 / 8; i += 256) {
            *reinterpret_cast<uint4*>(dst + i * 8) =
                *reinterpret_cast<const uint4*>(src + i * 8);
        }
    }
    if (tid < 128) labs[tid] = Y[seg * 128 + tid];
    __syncthreads();

    const int jq = tid & 31;              // j = jq*4 .. +3
    const int c0 = tid >> 5;              // 0..7; handles c0 and c0+8
    f32x4 acc0 = {0.f, 0.f, 0.f, 0.f};
    f32x4 acc1 = {0.f, 0.f, 0.f, 0.f};
    int cnt0 = 0, cnt1 = 0;
    for (int r = 0; r < 128; ++r) {
        ushort4 v = *reinterpret_cast<const ushort4*>(&rows_s[r][jq * 4]);
        const float f0 = bf_to_f(v.x), f1 = bf_to_f(v.y);
        const float f2 = bf_to_f(v.z), f3 = bf_to_f(v.w);
        const int lab = labs[r];
        const float h0 = (lab == c0) ? 1.f : 0.f;
        const float h1 = (lab == c0 + 8) ? 1.f : 0.f;
        acc0.x = fmaf(h0, f0, acc0.x); acc0.y = fmaf(h0, f1, acc0.y);
        acc0.z = fmaf(h0, f2, acc0.z); acc0.w = fmaf(h0, f3, acc0.w);
        acc1.x = fmaf(h1, f0, acc1.x); acc1.y = fmaf(h1, f1, acc1.y);
        acc1.z = fmaf(h1, f2, acc1.z); acc1.w = fmaf(h1, f3, acc1.w);
        cnt0 += (lab == c0);
        cnt1 += (lab == c0 + 8);
    }
    {
        unsigned short* pd = (unsigned short*)pdist;
        const size_t b0 = ((size_t)(batch * 16 + c0) * 128 + jq * 4) * 32 + seg;
        const size_t b1 = ((size_t)(batch * 16 + c0 + 8) * 128 + jq * 4) * 32 + seg;
        pd[b0 +  0] = (unsigned short)cvt_bf16(acc0.x);
        pd[b0 + 32] = (unsigned short)cvt_bf16(acc0.y);
        pd[b0 + 64] = (unsigned short)cvt_bf16(acc0.z);
        pd[b0 + 96] = (unsigned short)cvt_bf16(acc0.w);
        pd[b1 +  0] = (unsigned short)cvt_bf16(acc1.x);
        pd[b1 + 32] = (unsigned short)cvt_bf16(acc1.y);
        pd[b1 + 64] = (unsigned short)cvt_bf16(acc1.z);
        pd[b1 + 96] = (unsigned short)cvt_bf16(acc1.w);
    }
    if (jq == 0) {
        pcnt[(batch * 16 + c0) * 32 + seg]     = (float)cnt0;
        pcnt[(batch * 16 + c0 + 8) * 32 + seg] = (float)cnt1;
    }
}

// ---------------- K3: merge partials, means, logs, tiled KL, loss ----------
// Unified 32-row arrays: rows 0-15 = class means, rows 16-31 = mixture M.
// Stride 132 floats: 528 B (16B-aligned for b128), worst 4-way bank conflict.
__global__ __launch_bounds__(512) void final_kernel(
    const __hip_bfloat16* __restrict__ pdist, const float* __restrict__ pcnt,
    float* __restrict__ out)
{
    __shared__ float P_A[32][132], L_A[32][132];   // 2 x 16.5 KB
    __shared__ float P_B[32][132], L_B[32][132];   // 2 x 16.5 KB
    __shared__ float JA[32][32], JB[32][32];       // 8 KB
    __shared__ float pls[32];
    __shared__ float cnt[32];
    __shared__ float HA[32], HB[32];
    const int tid = threadIdx.x;
    const unsigned short* __restrict__ pd = (const unsigned short*)pdist;

    if (tid < 32) {
        float s = 0.f;
        #pragma unroll 8
        for (int seg = 0; seg < 32; ++seg) s += pcnt[tid * 32 + seg];
        cnt[tid] = s;
    }

    // merge 32 seg-partials per (bc, j) slot: contiguous 32 bf16 = 4 uint4
    for (int s = tid; s < 32 * NBINS; s += 512) {
        const int bc = s >> 7, jj = s & 127;
        const uint4* base = reinterpret_cast<const uint4*>(pd + (size_t)s * 32);
        float a = 0.f;
        #pragma unroll
        for (int w = 0; w < 4; ++w) {
            uint4 u = base[w];
            const unsigned short* us = (const unsigned short*)&u;
            #pragma unroll
            for (int e = 0; e < 8; ++e) a += bf_to_f(us[e]);
        }
        if (bc < 16) P_A[bc][jj] = a;
        else         P_B[bc - 16][jj] = a;
    }
    __syncthreads();

    // class means, mixture (rows 16-31), logs (mixture log computed once)
    for (int s = tid; s < NCLS * NBINS; s += 512) {
        const int c = s >> 7, jj = s & 127;
        const float a = P_A[c][jj] / cnt[c];
        const float b = P_B[c][jj] / cnt[16 + c];
        const float mm = 0.5f * (a + b);
        const float lm = __logf(mm);
        P_A[c][jj] = a;        L_A[c][jj] = __logf(a);
        P_A[c + 16][jj] = mm;  L_A[c + 16][jj] = lm;
        P_B[c][jj] = b;        L_B[c][jj] = __logf(b);
        P_B[c + 16][jj] = mm;  L_B[c + 16][jj] = lm;
    }
    __syncthreads();

    // self terms H[i] = sum_j P[i][j] * L[i][j], float4 reads
    if (tid < 64) {
        const int i = tid & 31;
        const float4* Pv = reinterpret_cast<const float4*>(
            (tid < 32) ? &P_A[i][0] : &P_B[i][0]);
        const float4* Lv = reinterpret_cast<const float4*>(
            (tid < 32) ? &L_A[i][0] : &L_B[i][0]);
        float h = 0.f;
        #pragma unroll 4
        for (int q = 0; q < 32; ++q) {
            float4 p = Pv[q], l = Lv[q];
            h = fmaf(p.x, l.x, h); h = fmaf(p.y, l.y, h);
            h = fmaf(p.z, l.z, h); h = fmaf(p.w, l.w, h);
        }
        if (tid < 32) HA[i] = h; else HB[i] = h;
    }
    __syncthreads();

    // KL cross terms: 4x4 register tile per thread, float4 LDS reads.
    // 128 threads: tid>>6 = side (A/B), t=tid&63 -> (i0,k0) 4x4 tile.
    if (tid < 128) {
        const int side = tid >> 6;
        const int t = tid & 63;
        const int i0 = (t >> 3) << 2, k0 = (t & 7) << 2;
        const float4* pr[4];
        const float4* lq[4];
        #pragma unroll
        for (int a = 0; a < 4; ++a) {
            pr[a] = reinterpret_cast<const float4*>(
                side ? &P_B[i0 + a][0] : &P_A[i0 + a][0]);
            lq[a] = reinterpret_cast<const float4*>(
                side ? &L_B[k0 + a][0] : &L_A[k0 + a][0]);
        }
        float accv[4][4];
        #pragma unroll
        for (int a = 0; a < 4; ++a)
            #pragma unroll
            for (int b = 0; b < 4; ++b) accv[a][b] = 0.f;
        for (int q = 0; q < 32; ++q) {
            float4 Pv[4], Lv[4];
            #pragma unroll
            for (int a = 0; a < 4; ++a) { Pv[a] = pr[a][q]; Lv[a] = lq[a][q]; }
            #pragma unroll
            for (int a = 0; a < 4; ++a)
                #pragma unroll
                for (int b = 0; b < 4; ++b) {
                    accv[a][b] = fmaf(Pv[a].x, Lv[b].x, accv[a][b]);
                    accv[a][b] = fmaf(Pv[a].y, Lv[b].y, accv[a][b]);
                    accv[a][b] = fmaf(Pv[a].z, Lv[b].z, accv[a][b]);
                    accv[a][b] = fmaf(Pv[a].w, Lv[b].w, accv[a][b]);
                }
        }
        float (*Jout)[32] = side ? JB : JA;
        #pragma unroll
        for (int a = 0; a < 4; ++a)
            #pragma unroll
            for (int b = 0; b < 4; ++b)
                Jout[i0 + a][k0 + b] = accv[a][b];
    }
    __syncthreads();

    // combine: J[i][k] = 0.5*((HA[i]-crossA) + (HB[i]-crossB)), diag = 0
    for (int p = tid; p < 32 * 32; p += 512) {
        const int i = p >> 5, k = p & 31;
        const float Jv = (i == k) ? 0.f
            : 0.5f * ((HA[i] - JA[i][k]) + (HB[i] - JB[i][k]));
        JA[i][k] = Jv;
    }
    __syncthreads();

    if (tid < 32) {
        float den = 0.f;
        for (int k = 0; k < 32; ++k) den += __expf(JA[tid][k] * (1.0f / TAUV));
        const float pos = JA[tid][(tid + 16) & 31];
        pls[tid] = -(pos * (1.0f / TAUV)) + __logf(den);
    }
    __syncthreads();
    if (tid == 0) {
        float s = 0.f;
        for (int i = 0; i < 32; ++i) s += pls[i];
        out[0] = s * (1.0f / 32.0f);
    }
}

extern "C" void kernel_launch(void* const* d_in, const int* in_sizes, int n_in,
                              void* d_out, int out_size, void* d_ws, size_t ws_size,
                              hipStream_t stream)
{
    const float* x1   = (const float*)d_in[0];
    const int*   y1   = (const int*)d_in[1];
    const float* x2   = (const float*)d_in[2];
    const int*   y2   = (const int*)d_in[3];
    const float* W1   = (const float*)d_in[4];
    const float* b1   = (const float*)d_in[5];
    const float* W2   = (const float*)d_in[6];
    const float* b2   = (const float*)d_in[7];
    const float* bins = (const float*)d_in[8];
    float* out = (float*)d_out;

    char* ws = (char*)d_ws;
    __hip_bfloat16* SMb = (__hip_bfloat16*)ws;                    // 2 MB
    char* ws2 = ws + (size_t)8192 * 128 * 2;
    __hip_bfloat16* pdist = (__hip_bfloat16*)ws2;                 // 32*128*32 bf16 = 256 KB
    float* pcnt = (float*)(ws2 + (size_t)32 * NBINS * 32 * 2);    // 32*32 f32
    __hip_bfloat16* W1T = (__hip_bfloat16*)(ws2 + (size_t)32 * NBINS * 32 * 2 + 8192);
    __hip_bfloat16* W2T = W1T + (size_t)OUT_F * IN_F;

    prep_w<<<128, 128, 0, stream>>>(W1, W2, W1T, W2T);
    fused_proj_pdf<<<512, 512, 0, stream>>>(x1, x2, W1T, b1, W2T, b2, bins, SMb);
    rowred_kernel<<<64, 256, 0, stream>>>(SMb, y1, y2, pdist, pcnt);
    final_kernel<<<1, 512, 0, stream>>>(pdist, pcnt, out);
}